// Round 1
// baseline (4588.200 us; speedup 1.0000x reference)
//
#include <hip/hip_runtime.h>
#include <math.h>

#define SEQ   2048
#define HSZ   2048
#define NHQ   16
#define NKV   8
#define HD    128
#define IMS   6144
#define EPSF  1e-6f
#define QT    4

// ---------------- row-wise RMSNorm (ncols multiple of 1024) ----------------
__global__ __launch_bounds__(256) void rmsnorm_kernel(
    const float* __restrict__ x, const float* __restrict__ w,
    float* __restrict__ out, int ncols)
{
    const int row = blockIdx.x;
    const float* xr = x + (size_t)row * ncols;
    float* orow = out + (size_t)row * ncols;
    float ssq = 0.f;
    for (int c = threadIdx.x * 4; c < ncols; c += 256 * 4) {
        float4 v = *reinterpret_cast<const float4*>(xr + c);
        ssq += v.x*v.x + v.y*v.y + v.z*v.z + v.w*v.w;
    }
#pragma unroll
    for (int off = 32; off; off >>= 1) ssq += __shfl_down(ssq, off, 64);
    __shared__ float red[4];
    __shared__ float rs_s;
    if ((threadIdx.x & 63) == 0) red[threadIdx.x >> 6] = ssq;
    __syncthreads();
    if (threadIdx.x == 0) {
        float t = red[0] + red[1] + red[2] + red[3];
        rs_s = rsqrtf(t / (float)ncols + EPSF);
    }
    __syncthreads();
    const float rs = rs_s;
    for (int c = threadIdx.x * 4; c < ncols; c += 256 * 4) {
        float4 v = *reinterpret_cast<const float4*>(xr + c);
        float4 g = *reinterpret_cast<const float4*>(w + c);
        float4 o;
        o.x = v.x * rs * g.x; o.y = v.y * rs * g.y;
        o.z = v.z * rs * g.z; o.w = v.w * rs * g.w;
        *reinterpret_cast<float4*>(orow + c) = o;
    }
}

// ---------------- SGEMM: C[M,N] = A[M,K] @ B[K,N] (+ R) ----------------
// 128x128 tile, BK=16, 256 threads, 8x8 per thread.
__global__ __launch_bounds__(256) void sgemm128(
    const float* __restrict__ A, const float* __restrict__ B,
    const float* __restrict__ R, float* __restrict__ C,
    int M, int N, int K)
{
    __shared__ float As[16][128];
    __shared__ float Bs[16][128];
    const int tid = threadIdx.x;
    const int tx = tid & 15;          // output col group
    const int ty = tid >> 4;          // output row group
    const int bm = blockIdx.y, bn = blockIdx.x;
    const int arow = tid >> 2;        // 0..63
    const int acol = (tid & 3) << 2;  // 0,4,8,12
    const int brow = tid >> 5;        // 0..7
    const int bcol = (tid & 31) << 2; // 0..124
    const float* Ap = A + (size_t)(bm * 128 + arow) * K + acol;
    const float* Bp = B + (size_t)brow * N + bn * 128 + bcol;
    float acc[8][8] = {};
    for (int k0 = 0; k0 < K; k0 += 16) {
        float4 a0 = *reinterpret_cast<const float4*>(Ap + k0);
        float4 a1 = *reinterpret_cast<const float4*>(Ap + (size_t)64 * K + k0);
        float4 b0 = *reinterpret_cast<const float4*>(Bp + (size_t)k0 * N);
        float4 b1 = *reinterpret_cast<const float4*>(Bp + (size_t)(k0 + 8) * N);
        __syncthreads();
        As[acol + 0][arow] = a0.x; As[acol + 1][arow] = a0.y;
        As[acol + 2][arow] = a0.z; As[acol + 3][arow] = a0.w;
        As[acol + 0][arow + 64] = a1.x; As[acol + 1][arow + 64] = a1.y;
        As[acol + 2][arow + 64] = a1.z; As[acol + 3][arow + 64] = a1.w;
        *reinterpret_cast<float4*>(&Bs[brow][bcol]) = b0;
        *reinterpret_cast<float4*>(&Bs[brow + 8][bcol]) = b1;
        __syncthreads();
#pragma unroll
        for (int kk = 0; kk < 16; ++kk) {
            float4 av0 = *reinterpret_cast<const float4*>(&As[kk][ty * 8]);
            float4 av1 = *reinterpret_cast<const float4*>(&As[kk][ty * 8 + 4]);
            float4 bv0 = *reinterpret_cast<const float4*>(&Bs[kk][tx * 8]);
            float4 bv1 = *reinterpret_cast<const float4*>(&Bs[kk][tx * 8 + 4]);
            float a[8] = {av0.x, av0.y, av0.z, av0.w, av1.x, av1.y, av1.z, av1.w};
            float b[8] = {bv0.x, bv0.y, bv0.z, bv0.w, bv1.x, bv1.y, bv1.z, bv1.w};
#pragma unroll
            for (int i = 0; i < 8; ++i)
#pragma unroll
                for (int j = 0; j < 8; ++j)
                    acc[i][j] += a[i] * b[j];
        }
    }
    const int row0 = bm * 128 + ty * 8;
    const int col0 = bn * 128 + tx * 8;
#pragma unroll
    for (int i = 0; i < 8; ++i) {
        size_t off = (size_t)(row0 + i) * N + col0;
        float4 o0 = make_float4(acc[i][0], acc[i][1], acc[i][2], acc[i][3]);
        float4 o1 = make_float4(acc[i][4], acc[i][5], acc[i][6], acc[i][7]);
        if (R) {
            float4 r0 = *reinterpret_cast<const float4*>(R + off);
            float4 r1 = *reinterpret_cast<const float4*>(R + off + 4);
            o0.x += r0.x; o0.y += r0.y; o0.z += r0.z; o0.w += r0.w;
            o1.x += r1.x; o1.y += r1.y; o1.z += r1.z; o1.w += r1.w;
        }
        *reinterpret_cast<float4*>(C + off) = o0;
        *reinterpret_cast<float4*>(C + off + 4) = o1;
    }
}

// ---------------- per-head RMSNorm + RoPE (in place) ----------------
__global__ __launch_bounds__(128) void qknorm_rope_kernel(
    float* __restrict__ x, const float* __restrict__ w,
    const int* __restrict__ pos, int nheads)
{
    const int blk = blockIdx.x;
    const int s = blk / nheads, hh = blk - s * nheads;
    float* xr = x + ((size_t)s * nheads + hh) * HD;
    const int d = threadIdx.x;
    float vv = xr[d];
    float ssq = vv * vv;
#pragma unroll
    for (int off = 32; off; off >>= 1) ssq += __shfl_down(ssq, off, 64);
    __shared__ float red2[2];
    __shared__ float xn[HD];
    if ((d & 63) == 0) red2[d >> 6] = ssq;
    __syncthreads();
    const float rs = rsqrtf((red2[0] + red2[1]) * (1.f / HD) + EPSF);
    const float nv = vv * rs * w[d];
    xn[d] = nv;
    __syncthreads();
    const float p = (float)pos[s];
    const int i = d & 63;
    // inv_freq = 10000^(-i/64) = exp(-ln(10000)/64 * i)
    const float inv_freq = expf(-0.14391156698f * (float)i);
    const float ang = p * inv_freq;
    float sn, cs;
    sincosf(ang, &sn, &cs);
    const float rot = (d < 64) ? -xn[d + 64] : xn[d - 64];
    xr[d] = nv * cs + rot * sn;
}

// ---------------- causal GQA attention, 4 queries per block ----------------
__global__ __launch_bounds__(256) void attn_kernel(
    const float* __restrict__ Q, const float* __restrict__ K,
    const float* __restrict__ V, float* __restrict__ O)
{
    const int h   = blockIdx.y;
    const int q0  = blockIdx.x * QT;
    const int kvh = h / (NHQ / NKV);
    const int tid = threadIdx.x;

    __shared__ float qs[QT][HD];
    __shared__ float sc[QT][SEQ];
    __shared__ float red[4];
    __shared__ float bc;

    for (int i = tid; i < QT * HD; i += 256) {
        int qt = i >> 7, d = i & 127;
        qs[qt][d] = Q[(size_t)(q0 + qt) * (NHQ * HD) + h * HD + d];
    }
    __syncthreads();

    const int qmax = q0 + QT - 1;
    const float scale = 0.08838834764831845f;  // 1/sqrt(128)

    // scores for all keys j <= qmax
    for (int j = tid; j <= qmax; j += 256) {
        const float* kr = K + (size_t)j * (NKV * HD) + kvh * HD;
        float a0 = 0.f, a1 = 0.f, a2 = 0.f, a3 = 0.f;
#pragma unroll 4
        for (int d = 0; d < HD; ++d) {
            float kv = kr[d];
            a0 += kv * qs[0][d];
            a1 += kv * qs[1][d];
            a2 += kv * qs[2][d];
            a3 += kv * qs[3][d];
        }
        sc[0][j] = a0 * scale; sc[1][j] = a1 * scale;
        sc[2][j] = a2 * scale; sc[3][j] = a3 * scale;
    }
    __syncthreads();

    // exact softmax per query (causal: keys < cnt)
    for (int qt = 0; qt < QT; ++qt) {
        const int cnt = q0 + qt + 1;
        float lm = -INFINITY;
        for (int j = tid; j < cnt; j += 256) lm = fmaxf(lm, sc[qt][j]);
#pragma unroll
        for (int off = 32; off; off >>= 1) lm = fmaxf(lm, __shfl_down(lm, off, 64));
        if ((tid & 63) == 0) red[tid >> 6] = lm;
        __syncthreads();
        if (tid == 0) bc = fmaxf(fmaxf(red[0], red[1]), fmaxf(red[2], red[3]));
        __syncthreads();
        const float m = bc;
        float ls = 0.f;
        for (int j = tid; j < cnt; j += 256) {
            float e = expf(sc[qt][j] - m);
            sc[qt][j] = e;
            ls += e;
        }
#pragma unroll
        for (int off = 32; off; off >>= 1) ls += __shfl_down(ls, off, 64);
        if ((tid & 63) == 0) red[tid >> 6] = ls;
        __syncthreads();
        if (tid == 0) bc = red[0] + red[1] + red[2] + red[3];
        __syncthreads();
        const float inv = 1.f / bc;
        for (int j = tid; j < cnt; j += 256) sc[qt][j] *= inv;
        for (int j = cnt + tid; j <= qmax; j += 256) sc[qt][j] = 0.f;
        __syncthreads();
    }

    // P @ V : thread owns one d, two queries
    const int d = tid & 127;
    const int half = tid >> 7;
    const float* vb = V + (size_t)kvh * HD + d;
    const float* p0 = &sc[half][0];
    const float* p1 = &sc[half + 2][0];
    float acc0 = 0.f, acc1 = 0.f;
#pragma unroll 4
    for (int j = 0; j <= qmax; ++j) {
        float vv = vb[(size_t)j * (NKV * HD)];
        acc0 += p0[j] * vv;
        acc1 += p1[j] * vv;
    }
    O[(size_t)(q0 + half) * (NHQ * HD) + h * HD + d] = acc0;
    O[(size_t)(q0 + half + 2) * (NHQ * HD) + h * HD + d] = acc1;
}

// ---------------- silu(gate) * up ----------------
__global__ __launch_bounds__(256) void silu_mul_kernel(
    const float* __restrict__ g, const float* __restrict__ u,
    float* __restrict__ o, int n4)
{
    int i = blockIdx.x * 256 + threadIdx.x;
    if (i < n4) {
        float4 gv = reinterpret_cast<const float4*>(g)[i];
        float4 uv = reinterpret_cast<const float4*>(u)[i];
        float4 ov;
        ov.x = gv.x / (1.f + expf(-gv.x)) * uv.x;
        ov.y = gv.y / (1.f + expf(-gv.y)) * uv.y;
        ov.z = gv.z / (1.f + expf(-gv.z)) * uv.z;
        ov.w = gv.w / (1.f + expf(-gv.w)) * uv.w;
        reinterpret_cast<float4*>(o)[i] = ov;
    }
}

extern "C" void kernel_launch(void* const* d_in, const int* in_sizes, int n_in,
                              void* d_out, int out_size, void* d_ws, size_t ws_size,
                              hipStream_t stream)
{
    const float* x     = (const float*)d_in[0];
    const int*   pos   = (const int*)d_in[1];
    const float* w_in  = (const float*)d_in[2];
    const float* wq    = (const float*)d_in[3];
    const float* wk    = (const float*)d_in[4];
    const float* wv    = (const float*)d_in[5];
    const float* qnw   = (const float*)d_in[6];
    const float* knw   = (const float*)d_in[7];
    const float* wo    = (const float*)d_in[8];
    const float* wpost = (const float*)d_in[9];
    const float* wgate = (const float*)d_in[10];
    const float* wup   = (const float*)d_in[11];
    const float* wdown = (const float*)d_in[12];
    float* out = (float*)d_out;

    float* ws   = (float*)d_ws;
    float* h    = ws;                          // SEQ*HSZ      (norm out, later attn out)
    float* q    = h + (size_t)SEQ * HSZ;       // SEQ*NHQ*HD   (q, later h2)
    float* k    = q + (size_t)SEQ * NHQ * HD;  // SEQ*NKV*HD
    float* v    = k + (size_t)SEQ * NKV * HD;  // SEQ*NKV*HD
    float* gate = v + (size_t)SEQ * NKV * HD;  // SEQ*IMS
    float* up   = gate + (size_t)SEQ * IMS;    // SEQ*IMS
    // total ws: ~151 MB

    // h = rmsnorm(x)
    rmsnorm_kernel<<<SEQ, 256, 0, stream>>>(x, w_in, h, HSZ);
    // q,k,v projections
    sgemm128<<<dim3((NHQ * HD) / 128, SEQ / 128), 256, 0, stream>>>(h, wq, nullptr, q, SEQ, NHQ * HD, HSZ);
    sgemm128<<<dim3((NKV * HD) / 128, SEQ / 128), 256, 0, stream>>>(h, wk, nullptr, k, SEQ, NKV * HD, HSZ);
    sgemm128<<<dim3((NKV * HD) / 128, SEQ / 128), 256, 0, stream>>>(h, wv, nullptr, v, SEQ, NKV * HD, HSZ);
    // per-head qk-norm + rope (in place)
    qknorm_rope_kernel<<<SEQ * NHQ, 128, 0, stream>>>(q, qnw, pos, NHQ);
    qknorm_rope_kernel<<<SEQ * NKV, 128, 0, stream>>>(k, knw, pos, NKV);
    // causal GQA attention -> h (reuse)
    attn_kernel<<<dim3(SEQ / QT, NHQ), 256, 0, stream>>>(q, k, v, h);
    // x2 = attn @ wo + x  -> out (d_out doubles as residual buffer)
    sgemm128<<<dim3(HSZ / 128, SEQ / 128), 256, 0, stream>>>(h, wo, x, out, SEQ, HSZ, NHQ * HD);
    // h2 = rmsnorm(x2) -> q (reuse)
    rmsnorm_kernel<<<SEQ, 256, 0, stream>>>(out, wpost, q, HSZ);
    // gate / up
    sgemm128<<<dim3(IMS / 128, SEQ / 128), 256, 0, stream>>>(q, wgate, nullptr, gate, SEQ, IMS, HSZ);
    sgemm128<<<dim3(IMS / 128, SEQ / 128), 256, 0, stream>>>(q, wup, nullptr, up, SEQ, IMS, HSZ);
    // gate = silu(gate) * up
    silu_mul_kernel<<<(SEQ * IMS / 4 + 255) / 256, 256, 0, stream>>>(gate, up, gate, SEQ * IMS / 4);
    // out = gate @ wdown + x2
    sgemm128<<<dim3(HSZ / 128, SEQ / 128), 256, 0, stream>>>(gate, wdown, out, out, SEQ, HSZ, IMS);
}

// Round 2
// 3716.155 us; speedup vs baseline: 1.2347x; 1.2347x over previous
//
#include <hip/hip_runtime.h>
#include <math.h>

#define SEQ   2048
#define HSZ   2048
#define NHQ   16
#define NKV   8
#define HD    128
#define IMS   6144
#define EPSF  1e-6f

// ---------------- row-wise RMSNorm (ncols multiple of 1024) ----------------
__global__ __launch_bounds__(256) void rmsnorm_kernel(
    const float* __restrict__ x, const float* __restrict__ w,
    float* __restrict__ out, int ncols)
{
    const int row = blockIdx.x;
    const float* xr = x + (size_t)row * ncols;
    float* orow = out + (size_t)row * ncols;
    float ssq = 0.f;
    for (int c = threadIdx.x * 4; c < ncols; c += 256 * 4) {
        float4 v = *reinterpret_cast<const float4*>(xr + c);
        ssq += v.x*v.x + v.y*v.y + v.z*v.z + v.w*v.w;
    }
#pragma unroll
    for (int off = 32; off; off >>= 1) ssq += __shfl_down(ssq, off, 64);
    __shared__ float red[4];
    __shared__ float rs_s;
    if ((threadIdx.x & 63) == 0) red[threadIdx.x >> 6] = ssq;
    __syncthreads();
    if (threadIdx.x == 0) {
        float t = red[0] + red[1] + red[2] + red[3];
        rs_s = rsqrtf(t / (float)ncols + EPSF);
    }
    __syncthreads();
    const float rs = rs_s;
    for (int c = threadIdx.x * 4; c < ncols; c += 256 * 4) {
        float4 v = *reinterpret_cast<const float4*>(xr + c);
        float4 g = *reinterpret_cast<const float4*>(w + c);
        float4 o;
        o.x = v.x * rs * g.x; o.y = v.y * rs * g.y;
        o.z = v.z * rs * g.z; o.w = v.w * rs * g.w;
        *reinterpret_cast<float4*>(orow + c) = o;
    }
}

// ---------------- SGEMM: C[M,N] = A[M,K] @ B[K,N] (+ R) ----------------
// 128x128 tile, BK=16, 256 threads, 8x8 per thread, reg-prefetch pipeline.
__global__ __launch_bounds__(256) void sgemm128(
    const float* __restrict__ A, const float* __restrict__ B,
    const float* __restrict__ R, float* __restrict__ C,
    int M, int N, int K)
{
    __shared__ float As[16][128];
    __shared__ float Bs[16][128];
    const int tid = threadIdx.x;
    const int tx = tid & 15;
    const int ty = tid >> 4;
    const int bm = blockIdx.y, bn = blockIdx.x;
    const int arow = tid >> 2;
    const int acol = (tid & 3) << 2;
    const int brow = tid >> 5;
    const int bcol = (tid & 31) << 2;
    const float* Ap = A + (size_t)(bm * 128 + arow) * K + acol;
    const float* Bp = B + (size_t)brow * N + bn * 128 + bcol;
    float acc[8][8] = {};

    float4 a0 = *reinterpret_cast<const float4*>(Ap);
    float4 a1 = *reinterpret_cast<const float4*>(Ap + (size_t)64 * K);
    float4 b0 = *reinterpret_cast<const float4*>(Bp);
    float4 b1 = *reinterpret_cast<const float4*>(Bp + (size_t)8 * N);

    for (int k0 = 0;;) {
        __syncthreads();
        As[acol + 0][arow] = a0.x; As[acol + 1][arow] = a0.y;
        As[acol + 2][arow] = a0.z; As[acol + 3][arow] = a0.w;
        As[acol + 0][arow + 64] = a1.x; As[acol + 1][arow + 64] = a1.y;
        As[acol + 2][arow + 64] = a1.z; As[acol + 3][arow + 64] = a1.w;
        *reinterpret_cast<float4*>(&Bs[brow][bcol]) = b0;
        *reinterpret_cast<float4*>(&Bs[brow + 8][bcol]) = b1;
        __syncthreads();
        const int kn = k0 + 16;
        float4 na0, na1, nb0, nb1;
        if (kn < K) {   // prefetch next tile: latency hides under the FMA loop
            na0 = *reinterpret_cast<const float4*>(Ap + kn);
            na1 = *reinterpret_cast<const float4*>(Ap + (size_t)64 * K + kn);
            nb0 = *reinterpret_cast<const float4*>(Bp + (size_t)kn * N);
            nb1 = *reinterpret_cast<const float4*>(Bp + (size_t)(kn + 8) * N);
        }
#pragma unroll
        for (int kk = 0; kk < 16; ++kk) {
            float4 av0 = *reinterpret_cast<const float4*>(&As[kk][ty * 8]);
            float4 av1 = *reinterpret_cast<const float4*>(&As[kk][ty * 8 + 4]);
            float4 bv0 = *reinterpret_cast<const float4*>(&Bs[kk][tx * 8]);
            float4 bv1 = *reinterpret_cast<const float4*>(&Bs[kk][tx * 8 + 4]);
            float a[8] = {av0.x, av0.y, av0.z, av0.w, av1.x, av1.y, av1.z, av1.w};
            float b[8] = {bv0.x, bv0.y, bv0.z, bv0.w, bv1.x, bv1.y, bv1.z, bv1.w};
#pragma unroll
            for (int i = 0; i < 8; ++i)
#pragma unroll
                for (int j = 0; j < 8; ++j)
                    acc[i][j] += a[i] * b[j];
        }
        if (kn >= K) break;
        a0 = na0; a1 = na1; b0 = nb0; b1 = nb1;
        k0 = kn;
    }

    const int row0 = bm * 128 + ty * 8;
    const int col0 = bn * 128 + tx * 8;
#pragma unroll
    for (int i = 0; i < 8; ++i) {
        size_t off = (size_t)(row0 + i) * N + col0;
        float4 o0 = make_float4(acc[i][0], acc[i][1], acc[i][2], acc[i][3]);
        float4 o1 = make_float4(acc[i][4], acc[i][5], acc[i][6], acc[i][7]);
        if (R) {
            float4 r0 = *reinterpret_cast<const float4*>(R + off);
            float4 r1 = *reinterpret_cast<const float4*>(R + off + 4);
            o0.x += r0.x; o0.y += r0.y; o0.z += r0.z; o0.w += r0.w;
            o1.x += r1.x; o1.y += r1.y; o1.z += r1.z; o1.w += r1.w;
        }
        *reinterpret_cast<float4*>(C + off) = o0;
        *reinterpret_cast<float4*>(C + off + 4) = o1;
    }
}

// ---------------- per-head RMSNorm + RoPE (in place) ----------------
__global__ __launch_bounds__(128) void qknorm_rope_kernel(
    float* __restrict__ x, const float* __restrict__ w,
    const int* __restrict__ pos, int nheads)
{
    const int blk = blockIdx.x;
    const int s = blk / nheads, hh = blk - s * nheads;
    float* xr = x + ((size_t)s * nheads + hh) * HD;
    const int d = threadIdx.x;
    float vv = xr[d];
    float ssq = vv * vv;
#pragma unroll
    for (int off = 32; off; off >>= 1) ssq += __shfl_down(ssq, off, 64);
    __shared__ float red2[2];
    __shared__ float xn[HD];
    if ((d & 63) == 0) red2[d >> 6] = ssq;
    __syncthreads();
    const float rs = rsqrtf((red2[0] + red2[1]) * (1.f / HD) + EPSF);
    const float nv = vv * rs * w[d];
    xn[d] = nv;
    __syncthreads();
    const float p = (float)pos[s];
    const int i = d & 63;
    const float inv_freq = expf(-0.14391156698f * (float)i);
    const float ang = p * inv_freq;
    float sn, cs;
    sincosf(ang, &sn, &cs);
    const float rot = (d < 64) ? -xn[d + 64] : xn[d - 64];
    xr[d] = nv * cs + rot * sn;
}

// ---------------- flash-style causal GQA attention ----------------
// 64 queries x 64 keys per tile, 256 threads (16x16 grid, 4x4 scores).
// LDS: Qt[128][64] transposed (32KB) + KV[8192] time-shared K^T/V (32KB).
__global__ __launch_bounds__(256, 2) void attn2_kernel(
    const float* __restrict__ Q, const float* __restrict__ K,
    const float* __restrict__ V, float* __restrict__ O)
{
    __shared__ float Qt[128 * 64];
    __shared__ float KV[128 * 64];

    const int h = blockIdx.y;
    // big/small tile swizzle for load balance: pair tile i with 31-i
    const int bx = blockIdx.x;
    const int qt_idx = (bx & 1) ? (31 - (bx >> 1)) : (bx >> 1);
    const int q0 = qt_idx * 64;
    const int kvh = h >> 1;                 // GQA rep=2
    const int tid = threadIdx.x;
    const int tr = tid >> 4, tc = tid & 15;
    const int lane = tid & 63;
    const int gbase = lane & 48;            // 16-lane row-group base
    const int nt = (q0 >> 6) + 1;
    const float scale = 0.08838834764831845f;   // 1/sqrt(128)

    // ---- stage Q transposed + pre-scaled (once) ----
    {
        const int qr = tid & 63;
        const int dbase = (tid >> 6) * 4;
        const float* qp = Q + (size_t)(q0 + qr) * (NHQ * HD) + h * HD;
#pragma unroll
        for (int it = 0; it < 8; ++it) {
            const int d0 = dbase + it * 16;
            float4 qv = *reinterpret_cast<const float4*>(qp + d0);
            Qt[(d0 + 0) * 64 + qr] = qv.x * scale;
            Qt[(d0 + 1) * 64 + qr] = qv.y * scale;
            Qt[(d0 + 2) * 64 + qr] = qv.z * scale;
            Qt[(d0 + 3) * 64 + qr] = qv.w * scale;
        }
    }

    // ---- preload K tile 0 into regs (lane=j mapping: conflict-free LDS writes) ----
    const int kj = tid & 63;
    const int kd = (tid >> 6) * 4;
    const float* kbp = K + (size_t)kvh * HD + kd;
    float4 kreg[8];
#pragma unroll
    for (int it = 0; it < 8; ++it)
        kreg[it] = *reinterpret_cast<const float4*>(kbp + (size_t)kj * (NKV * HD) + it * 16);

    float sc[4][4], p[4][4];
    float4 oA[4], oB[4];
    float mrow[4], lrow[4];
#pragma unroll
    for (int i = 0; i < 4; ++i) {
        oA[i] = make_float4(0.f, 0.f, 0.f, 0.f);
        oB[i] = make_float4(0.f, 0.f, 0.f, 0.f);
        mrow[i] = -INFINITY; lrow[i] = 0.f;
    }

    for (int t = 0; t < nt; ++t) {
        const int j0 = t * 64;
        __syncthreads();                       // prior PV done reading KV
        // K regs -> LDS transposed KV[d][j]
#pragma unroll
        for (int it = 0; it < 8; ++it) {
            const int d0 = kd + it * 16;
            KV[(d0 + 0) * 64 + kj] = kreg[it].x;
            KV[(d0 + 1) * 64 + kj] = kreg[it].y;
            KV[(d0 + 2) * 64 + kj] = kreg[it].z;
            KV[(d0 + 3) * 64 + kj] = kreg[it].w;
        }
        // issue V loads for this tile (latency hides under scores)
        float4 vreg[8];
#pragma unroll
        for (int it = 0; it < 8; ++it) {
            const int idx = tid + it * 256;
            const int jj = idx >> 5, d0 = (idx & 31) * 4;
            vreg[it] = *reinterpret_cast<const float4*>(
                V + (size_t)(j0 + jj) * (NKV * HD) + kvh * HD + d0);
        }
        __syncthreads();

        // ---- scores: SC[4][4] = (Q*scale) @ K^T ----
#pragma unroll
        for (int i = 0; i < 4; ++i)
#pragma unroll
            for (int c = 0; c < 4; ++c) sc[i][c] = 0.f;
#pragma unroll 4
        for (int kk = 0; kk < 128; ++kk) {
            float4 qv = *reinterpret_cast<const float4*>(&Qt[kk * 64 + tr * 4]);
            float4 kv = *reinterpret_cast<const float4*>(&KV[kk * 64 + tc * 4]);
            float qa[4] = {qv.x, qv.y, qv.z, qv.w};
            float ka[4] = {kv.x, kv.y, kv.z, kv.w};
#pragma unroll
            for (int i = 0; i < 4; ++i)
#pragma unroll
                for (int c = 0; c < 4; ++c)
                    sc[i][c] += qa[i] * ka[c];
        }

        // ---- causal mask (diagonal tile only) ----
        if (j0 == q0) {
#pragma unroll
            for (int i = 0; i < 4; ++i) {
                const int r = tr * 4 + i;
#pragma unroll
                for (int c = 0; c < 4; ++c)
                    if (tc * 4 + c > r) sc[i][c] = -INFINITY;
            }
        }

        // ---- online softmax (row = 16 consecutive lanes) ----
#pragma unroll
        for (int i = 0; i < 4; ++i) {
            float rm = fmaxf(fmaxf(sc[i][0], sc[i][1]), fmaxf(sc[i][2], sc[i][3]));
            rm = fmaxf(rm, __shfl_xor(rm, 1, 64));
            rm = fmaxf(rm, __shfl_xor(rm, 2, 64));
            rm = fmaxf(rm, __shfl_xor(rm, 4, 64));
            rm = fmaxf(rm, __shfl_xor(rm, 8, 64));
            const float mnew = fmaxf(mrow[i], rm);
            const float fac = expf(mrow[i] - mnew);
            mrow[i] = mnew;
            float rs = 0.f;
#pragma unroll
            for (int c = 0; c < 4; ++c) {
                const float e = expf(sc[i][c] - mnew);
                p[i][c] = e; rs += e;
            }
            rs += __shfl_xor(rs, 1, 64);
            rs += __shfl_xor(rs, 2, 64);
            rs += __shfl_xor(rs, 4, 64);
            rs += __shfl_xor(rs, 8, 64);
            lrow[i] = lrow[i] * fac + rs;
            oA[i].x *= fac; oA[i].y *= fac; oA[i].z *= fac; oA[i].w *= fac;
            oB[i].x *= fac; oB[i].y *= fac; oB[i].z *= fac; oB[i].w *= fac;
        }

        __syncthreads();                       // all done reading K^T
        // V regs -> LDS row-major KV[j][d]
#pragma unroll
        for (int it = 0; it < 8; ++it) {
            const int idx = tid + it * 256;
            const int jj = idx >> 5, d0 = (idx & 31) * 4;
            *reinterpret_cast<float4*>(&KV[jj * 128 + d0]) = vreg[it];
        }
        // prefetch next K tile (latency hides under PV)
        if (t + 1 < nt) {
#pragma unroll
            for (int it = 0; it < 8; ++it)
                kreg[it] = *reinterpret_cast<const float4*>(
                    kbp + (size_t)((t + 1) * 64 + kj) * (NKV * HD) + it * 16);
        }
        __syncthreads();

        // ---- PV: O[4 rows][8 cols] += P @ V, P broadcast via shfl ----
#pragma unroll
        for (int j4 = 0; j4 < 16; ++j4) {
            float pb[4][4];
#pragma unroll
            for (int i = 0; i < 4; ++i)
#pragma unroll
                for (int c = 0; c < 4; ++c)
                    pb[i][c] = __shfl(p[i][c], gbase + j4, 64);
#pragma unroll
            for (int c = 0; c < 4; ++c) {
                const int j = j4 * 4 + c;
                float4 v0 = *reinterpret_cast<const float4*>(&KV[j * 128 + tc * 8]);
                float4 v1 = *reinterpret_cast<const float4*>(&KV[j * 128 + tc * 8 + 4]);
#pragma unroll
                for (int i = 0; i < 4; ++i) {
                    oA[i].x += pb[i][c] * v0.x; oA[i].y += pb[i][c] * v0.y;
                    oA[i].z += pb[i][c] * v0.z; oA[i].w += pb[i][c] * v0.w;
                    oB[i].x += pb[i][c] * v1.x; oB[i].y += pb[i][c] * v1.y;
                    oB[i].z += pb[i][c] * v1.z; oB[i].w += pb[i][c] * v1.w;
                }
            }
        }
    }

    // ---- epilogue: normalize + store ----
#pragma unroll
    for (int i = 0; i < 4; ++i) {
        const float inv = 1.f / lrow[i];
        float4 a = oA[i], b = oB[i];
        a.x *= inv; a.y *= inv; a.z *= inv; a.w *= inv;
        b.x *= inv; b.y *= inv; b.z *= inv; b.w *= inv;
        const size_t off = (size_t)(q0 + tr * 4 + i) * (NHQ * HD) + h * HD + tc * 8;
        *reinterpret_cast<float4*>(O + off) = a;
        *reinterpret_cast<float4*>(O + off + 4) = b;
    }
}

// ---------------- silu(gate) * up ----------------
__global__ __launch_bounds__(256) void silu_mul_kernel(
    const float* __restrict__ g, const float* __restrict__ u,
    float* __restrict__ o, int n4)
{
    int i = blockIdx.x * 256 + threadIdx.x;
    if (i < n4) {
        float4 gv = reinterpret_cast<const float4*>(g)[i];
        float4 uv = reinterpret_cast<const float4*>(u)[i];
        float4 ov;
        ov.x = gv.x / (1.f + expf(-gv.x)) * uv.x;
        ov.y = gv.y / (1.f + expf(-gv.y)) * uv.y;
        ov.z = gv.z / (1.f + expf(-gv.z)) * uv.z;
        ov.w = gv.w / (1.f + expf(-gv.w)) * uv.w;
        reinterpret_cast<float4*>(o)[i] = ov;
    }
}

extern "C" void kernel_launch(void* const* d_in, const int* in_sizes, int n_in,
                              void* d_out, int out_size, void* d_ws, size_t ws_size,
                              hipStream_t stream)
{
    const float* x     = (const float*)d_in[0];
    const int*   pos   = (const int*)d_in[1];
    const float* w_in  = (const float*)d_in[2];
    const float* wq    = (const float*)d_in[3];
    const float* wk    = (const float*)d_in[4];
    const float* wv    = (const float*)d_in[5];
    const float* qnw   = (const float*)d_in[6];
    const float* knw   = (const float*)d_in[7];
    const float* wo    = (const float*)d_in[8];
    const float* wpost = (const float*)d_in[9];
    const float* wgate = (const float*)d_in[10];
    const float* wup   = (const float*)d_in[11];
    const float* wdown = (const float*)d_in[12];
    float* out = (float*)d_out;

    float* ws   = (float*)d_ws;
    float* h    = ws;                          // SEQ*HSZ      (norm out, later attn out)
    float* q    = h + (size_t)SEQ * HSZ;       // SEQ*NHQ*HD   (q, later h2)
    float* k    = q + (size_t)SEQ * NHQ * HD;  // SEQ*NKV*HD
    float* v    = k + (size_t)SEQ * NKV * HD;  // SEQ*NKV*HD
    float* gate = v + (size_t)SEQ * NKV * HD;  // SEQ*IMS
    float* up   = gate + (size_t)SEQ * IMS;    // SEQ*IMS

    rmsnorm_kernel<<<SEQ, 256, 0, stream>>>(x, w_in, h, HSZ);
    sgemm128<<<dim3((NHQ * HD) / 128, SEQ / 128), 256, 0, stream>>>(h, wq, nullptr, q, SEQ, NHQ * HD, HSZ);
    sgemm128<<<dim3((NKV * HD) / 128, SEQ / 128), 256, 0, stream>>>(h, wk, nullptr, k, SEQ, NKV * HD, HSZ);
    sgemm128<<<dim3((NKV * HD) / 128, SEQ / 128), 256, 0, stream>>>(h, wv, nullptr, v, SEQ, NKV * HD, HSZ);
    qknorm_rope_kernel<<<SEQ * NHQ, 128, 0, stream>>>(q, qnw, pos, NHQ);
    qknorm_rope_kernel<<<SEQ * NKV, 128, 0, stream>>>(k, knw, pos, NKV);
    attn2_kernel<<<dim3(SEQ / 64, NHQ), 256, 0, stream>>>(q, k, v, h);
    sgemm128<<<dim3(HSZ / 128, SEQ / 128), 256, 0, stream>>>(h, wo, x, out, SEQ, HSZ, NHQ * HD);
    rmsnorm_kernel<<<SEQ, 256, 0, stream>>>(out, wpost, q, HSZ);
    sgemm128<<<dim3(IMS / 128, SEQ / 128), 256, 0, stream>>>(q, wgate, nullptr, gate, SEQ, IMS, HSZ);
    sgemm128<<<dim3(IMS / 128, SEQ / 128), 256, 0, stream>>>(q, wup, nullptr, up, SEQ, IMS, HSZ);
    silu_mul_kernel<<<(SEQ * IMS / 4 + 255) / 256, 256, 0, stream>>>(gate, up, gate, SEQ * IMS / 4);
    sgemm128<<<dim3(HSZ / 128, SEQ / 128), 256, 0, stream>>>(gate, wdown, out, out, SEQ, HSZ, IMS);
}

// Round 4
// 3246.045 us; speedup vs baseline: 1.4135x; 1.1448x over previous
//
#include <hip/hip_runtime.h>
#include <math.h>

#define SEQ   2048
#define HSZ   2048
#define NHQ   16
#define NKV   8
#define HD    128
#define IMS   6144
#define EPSF  1e-6f

typedef float f32x4 __attribute__((ext_vector_type(4)));
typedef short s16x8 __attribute__((ext_vector_type(8)));

__device__ __forceinline__ unsigned short f2bf(float f) {
    unsigned int u = __float_as_uint(f);
    unsigned int r = (u + 0x7FFFu + ((u >> 16) & 1u)) >> 16;   // RNE
    return (unsigned short)r;
}
__device__ __forceinline__ float bf2f(unsigned short h) {
    return __uint_as_float(((unsigned int)h) << 16);
}

// ---------------- row-wise RMSNorm -> fp32 ----------------
__global__ __launch_bounds__(256) void rmsnorm_kernel(
    const float* __restrict__ x, const float* __restrict__ w,
    float* __restrict__ out, int ncols)
{
    const int row = blockIdx.x;
    const float* xr = x + (size_t)row * ncols;
    float* orow = out + (size_t)row * ncols;
    float ssq = 0.f;
    for (int c = threadIdx.x * 4; c < ncols; c += 256 * 4) {
        float4 v = *reinterpret_cast<const float4*>(xr + c);
        ssq += v.x*v.x + v.y*v.y + v.z*v.z + v.w*v.w;
    }
#pragma unroll
    for (int off = 32; off; off >>= 1) ssq += __shfl_down(ssq, off, 64);
    __shared__ float red[4];
    __shared__ float rs_s;
    if ((threadIdx.x & 63) == 0) red[threadIdx.x >> 6] = ssq;
    __syncthreads();
    if (threadIdx.x == 0) {
        float t = red[0] + red[1] + red[2] + red[3];
        rs_s = rsqrtf(t / (float)ncols + EPSF);
    }
    __syncthreads();
    const float rs = rs_s;
    for (int c = threadIdx.x * 4; c < ncols; c += 256 * 4) {
        float4 v = *reinterpret_cast<const float4*>(xr + c);
        float4 g = *reinterpret_cast<const float4*>(w + c);
        float4 o;
        o.x = v.x * rs * g.x; o.y = v.y * rs * g.y;
        o.z = v.z * rs * g.z; o.w = v.w * rs * g.w;
        *reinterpret_cast<float4*>(orow + c) = o;
    }
}

// ------- RMSNorm -> bf16 hi/lo planes in A-role k-blocked layout -------
// planes: element (row m, col k) at P[((k>>3)*M + m)*8 + (k&7)]
__global__ __launch_bounds__(256) void rmsnorm_planes_kernel(
    const float* __restrict__ x, const float* __restrict__ w,
    unsigned short* __restrict__ Ph, unsigned short* __restrict__ Pl,
    int ncols, int M)
{
    const int row = blockIdx.x;
    const float* xr = x + (size_t)row * ncols;
    const int c0 = threadIdx.x * 8;   // ncols == 2048 == 256*8
    float4 v0 = *reinterpret_cast<const float4*>(xr + c0);
    float4 v1 = *reinterpret_cast<const float4*>(xr + c0 + 4);
    float ssq = v0.x*v0.x + v0.y*v0.y + v0.z*v0.z + v0.w*v0.w
              + v1.x*v1.x + v1.y*v1.y + v1.z*v1.z + v1.w*v1.w;
#pragma unroll
    for (int off = 32; off; off >>= 1) ssq += __shfl_down(ssq, off, 64);
    __shared__ float red[4];
    __shared__ float rs_s;
    if ((threadIdx.x & 63) == 0) red[threadIdx.x >> 6] = ssq;
    __syncthreads();
    if (threadIdx.x == 0)
        rs_s = rsqrtf((red[0] + red[1] + red[2] + red[3]) / (float)ncols + EPSF);
    __syncthreads();
    const float rs = rs_s;
    float vals[8] = {v0.x, v0.y, v0.z, v0.w, v1.x, v1.y, v1.z, v1.w};
    unsigned short hh[8], ll[8];
#pragma unroll
    for (int i = 0; i < 8; ++i) {
        float f = vals[i] * rs * w[c0 + i];
        hh[i] = f2bf(f);
        ll[i] = f2bf(f - bf2f(hh[i]));
    }
    const size_t boff = ((size_t)threadIdx.x * M + row) * 8;
    uint4 ph, pl;
    ph.x = hh[0] | (hh[1] << 16); ph.y = hh[2] | (hh[3] << 16);
    ph.z = hh[4] | (hh[5] << 16); ph.w = hh[6] | (hh[7] << 16);
    pl.x = ll[0] | (ll[1] << 16); pl.y = ll[2] | (ll[3] << 16);
    pl.z = ll[4] | (ll[5] << 16); pl.w = ll[6] | (ll[7] << 16);
    *reinterpret_cast<uint4*>(Ph + boff) = ph;
    *reinterpret_cast<uint4*>(Pl + boff) = pl;
}

// ------- weight fp32 [K][N] -> bf16 hi/lo planes, B-role k-blocked -------
// element (k,n) at P[((k>>3)*N + n)*8 + (k&7)]
__global__ __launch_bounds__(256) void wconv_kernel(
    const float* __restrict__ W, unsigned short* __restrict__ Ph,
    unsigned short* __restrict__ Pl, int Kd, int Nd)
{
    const int idx = blockIdx.x * 256 + threadIdx.x;   // one per (kb, n)
    const int total = (Kd >> 3) * Nd;
    if (idx >= total) return;
    const int kb = idx / Nd;
    const int n  = idx - kb * Nd;
    unsigned short hh[8], ll[8];
#pragma unroll
    for (int i = 0; i < 8; ++i) {
        float f = W[(size_t)(kb * 8 + i) * Nd + n];
        hh[i] = f2bf(f);
        ll[i] = f2bf(f - bf2f(hh[i]));
    }
    uint4 ph, pl;
    ph.x = hh[0] | (hh[1] << 16); ph.y = hh[2] | (hh[3] << 16);
    ph.z = hh[4] | (hh[5] << 16); ph.w = hh[6] | (hh[7] << 16);
    pl.x = ll[0] | (ll[1] << 16); pl.y = ll[2] | (ll[3] << 16);
    pl.z = ll[4] | (ll[5] << 16); pl.w = ll[6] | (ll[7] << 16);
    *reinterpret_cast<uint4*>(Ph + (size_t)idx * 8) = ph;
    *reinterpret_cast<uint4*>(Pl + (size_t)idx * 8) = pl;
}

// ---------------- SGEMM (fp32, kept for qkv + wo) ----------------
__global__ __launch_bounds__(256) void sgemm128(
    const float* __restrict__ A, const float* __restrict__ B,
    const float* __restrict__ R, float* __restrict__ C,
    int M, int N, int K)
{
    __shared__ float As[16][128];
    __shared__ float Bs[16][128];
    const int tid = threadIdx.x;
    const int tx = tid & 15;
    const int ty = tid >> 4;
    const int bm = blockIdx.y, bn = blockIdx.x;
    const int arow = tid >> 2;
    const int acol = (tid & 3) << 2;
    const int brow = tid >> 5;
    const int bcol = (tid & 31) << 2;
    const float* Ap = A + (size_t)(bm * 128 + arow) * K + acol;
    const float* Bp = B + (size_t)brow * N + bn * 128 + bcol;
    float acc[8][8] = {};

    float4 a0 = *reinterpret_cast<const float4*>(Ap);
    float4 a1 = *reinterpret_cast<const float4*>(Ap + (size_t)64 * K);
    float4 b0 = *reinterpret_cast<const float4*>(Bp);
    float4 b1 = *reinterpret_cast<const float4*>(Bp + (size_t)8 * N);

    for (int k0 = 0;;) {
        __syncthreads();
        As[acol + 0][arow] = a0.x; As[acol + 1][arow] = a0.y;
        As[acol + 2][arow] = a0.z; As[acol + 3][arow] = a0.w;
        As[acol + 0][arow + 64] = a1.x; As[acol + 1][arow + 64] = a1.y;
        As[acol + 2][arow + 64] = a1.z; As[acol + 3][arow + 64] = a1.w;
        *reinterpret_cast<float4*>(&Bs[brow][bcol]) = b0;
        *reinterpret_cast<float4*>(&Bs[brow + 8][bcol]) = b1;
        __syncthreads();
        const int kn = k0 + 16;
        float4 na0, na1, nb0, nb1;
        if (kn < K) {
            na0 = *reinterpret_cast<const float4*>(Ap + kn);
            na1 = *reinterpret_cast<const float4*>(Ap + (size_t)64 * K + kn);
            nb0 = *reinterpret_cast<const float4*>(Bp + (size_t)kn * N);
            nb1 = *reinterpret_cast<const float4*>(Bp + (size_t)(kn + 8) * N);
        }
#pragma unroll
        for (int kk = 0; kk < 16; ++kk) {
            float4 av0 = *reinterpret_cast<const float4*>(&As[kk][ty * 8]);
            float4 av1 = *reinterpret_cast<const float4*>(&As[kk][ty * 8 + 4]);
            float4 bv0 = *reinterpret_cast<const float4*>(&Bs[kk][tx * 8]);
            float4 bv1 = *reinterpret_cast<const float4*>(&Bs[kk][tx * 8 + 4]);
            float a[8] = {av0.x, av0.y, av0.z, av0.w, av1.x, av1.y, av1.z, av1.w};
            float b[8] = {bv0.x, bv0.y, bv0.z, bv0.w, bv1.x, bv1.y, bv1.z, bv1.w};
#pragma unroll
            for (int i = 0; i < 8; ++i)
#pragma unroll
                for (int j = 0; j < 8; ++j)
                    acc[i][j] += a[i] * b[j];
        }
        if (kn >= K) break;
        a0 = na0; a1 = na1; b0 = nb0; b1 = nb1;
        k0 = kn;
    }

    const int row0 = bm * 128 + ty * 8;
    const int col0 = bn * 128 + tx * 8;
#pragma unroll
    for (int i = 0; i < 8; ++i) {
        size_t off = (size_t)(row0 + i) * N + col0;
        float4 o0 = make_float4(acc[i][0], acc[i][1], acc[i][2], acc[i][3]);
        float4 o1 = make_float4(acc[i][4], acc[i][5], acc[i][6], acc[i][7]);
        if (R) {
            float4 r0 = *reinterpret_cast<const float4*>(R + off);
            float4 r1 = *reinterpret_cast<const float4*>(R + off + 4);
            o0.x += r0.x; o0.y += r0.y; o0.z += r0.z; o0.w += r0.w;
            o1.x += r1.x; o1.y += r1.y; o1.z += r1.z; o1.w += r1.w;
        }
        *reinterpret_cast<float4*>(C + off) = o0;
        *reinterpret_cast<float4*>(C + off + 4) = o1;
    }
}

// -------- MFMA bf16x3 GEMM: C = (Ah+Al)@(Bh+Bl), fp32 accumulate --------
// 128x128 tile, BK=32, 4 waves (wave tile 64x64 as 4x4 frags of 16x16x32).
// EPI 0: C = acc (+X residual).  EPI 1: planes(silu(X)*acc) -> Oh/Ol.
template<int EPI>
__global__ __launch_bounds__(256) void mgemm3(
    const unsigned short* __restrict__ Ah, const unsigned short* __restrict__ Al,
    const unsigned short* __restrict__ Bh, const unsigned short* __restrict__ Bl,
    const float* __restrict__ X, float* __restrict__ C,
    unsigned short* __restrict__ Oh, unsigned short* __restrict__ Ol,
    int M, int N, int K)
{
    __shared__ uint4 Sl[4][512];   // [plane Ah,Al,Bh,Bl][kb(4)*128 + idx] 16B blocks

    const int tid  = threadIdx.x;
    const int lane = tid & 63;
    const int wid  = tid >> 6;
    const int wm   = wid >> 1, wn = wid & 1;
    const int bm = blockIdx.y, bn = blockIdx.x;

    // staging assignment: wave = plane, 8 chunks of 64 blocks
    const uint4* gplane;
    {
        const unsigned short* p = (wid == 0) ? Ah : (wid == 1) ? Al : (wid == 2) ? Bh : Bl;
        gplane = reinterpret_cast<const uint4*>(p);
    }
    const int pdim  = (wid < 2) ? M : N;
    const int pbase = (wid < 2) ? bm * 128 : bn * 128;

    f32x4 acc[4][4];
#pragma unroll
    for (int i = 0; i < 4; ++i)
#pragma unroll
        for (int j = 0; j < 4; ++j)
            acc[i][j] = (f32x4){0.f, 0.f, 0.f, 0.f};

    const int steps = K >> 5;
    uint4 rg[8];
#pragma unroll
    for (int i = 0; i < 8; ++i) {
        const int kb = i >> 1, idx = (i & 1) * 64 + lane;
        rg[i] = gplane[(size_t)kb * pdim + pbase + idx];
    }

    for (int s = 0; s < steps; ++s) {
        __syncthreads();
#pragma unroll
        for (int i = 0; i < 8; ++i) {
            const int kb = i >> 1, idx = (i & 1) * 64 + lane;
            Sl[wid][kb * 128 + idx] = rg[i];
        }
        __syncthreads();
        if (s + 1 < steps) {
            const size_t kb0 = (size_t)(s + 1) * 4;
#pragma unroll
            for (int i = 0; i < 8; ++i) {
                const int kb = i >> 1, idx = (i & 1) * 64 + lane;
                rg[i] = gplane[(kb0 + kb) * pdim + pbase + idx];
            }
        }
        // fragments: kb = lane>>4, element = lane&15
        const int kq = (lane >> 4) * 128 + (lane & 15);
        s16x8 bh[4], bl[4];
#pragma unroll
        for (int nf = 0; nf < 4; ++nf) {
            bh[nf] = *reinterpret_cast<const s16x8*>(&Sl[2][kq + wn * 64 + nf * 16]);
            bl[nf] = *reinterpret_cast<const s16x8*>(&Sl[3][kq + wn * 64 + nf * 16]);
        }
#pragma unroll
        for (int mf = 0; mf < 4; ++mf) {
            s16x8 ah = *reinterpret_cast<const s16x8*>(&Sl[0][kq + wm * 64 + mf * 16]);
            s16x8 al = *reinterpret_cast<const s16x8*>(&Sl[1][kq + wm * 64 + mf * 16]);
#pragma unroll
            for (int nf = 0; nf < 4; ++nf) {
                acc[mf][nf] = __builtin_amdgcn_mfma_f32_16x16x32_bf16(ah, bh[nf], acc[mf][nf], 0, 0, 0);
                acc[mf][nf] = __builtin_amdgcn_mfma_f32_16x16x32_bf16(al, bh[nf], acc[mf][nf], 0, 0, 0);
                acc[mf][nf] = __builtin_amdgcn_mfma_f32_16x16x32_bf16(ah, bl[nf], acc[mf][nf], 0, 0, 0);
            }
        }
    }

    // epilogue: C/D layout col=lane&15, row=(lane>>4)*4+reg  [m89]
    const int lrow = (lane >> 4) * 4;
    const int lcol = lane & 15;
#pragma unroll
    for (int mf = 0; mf < 4; ++mf) {
#pragma unroll
        for (int nf = 0; nf < 4; ++nf) {
            const int col = bn * 128 + wn * 64 + nf * 16 + lcol;
            const int row0 = bm * 128 + wm * 64 + mf * 16 + lrow;
#pragma unroll
            for (int r = 0; r < 4; ++r) {
                const int row = row0 + r;
                float val = acc[mf][nf][r];
                if (EPI == 0) {
                    if (X) val += X[(size_t)row * N + col];
                    C[(size_t)row * N + col] = val;
                } else {
                    const float g = X[(size_t)row * N + col];
                    const float sg = g / (1.f + expf(-g));
                    const float v = sg * val;
                    const unsigned short h = f2bf(v);
                    const unsigned short l = f2bf(v - bf2f(h));
                    const size_t po = ((size_t)(col >> 3) * M + row) * 8 + (col & 7);
                    Oh[po] = h;
                    Ol[po] = l;
                }
            }
        }
    }
}

// ---------------- per-head RMSNorm + RoPE (in place) ----------------
__global__ __launch_bounds__(128) void qknorm_rope_kernel(
    float* __restrict__ x, const float* __restrict__ w,
    const int* __restrict__ pos, int nheads)
{
    const int blk = blockIdx.x;
    const int s = blk / nheads, hh = blk - s * nheads;
    float* xr = x + ((size_t)s * nheads + hh) * HD;
    const int d = threadIdx.x;
    float vv = xr[d];
    float ssq = vv * vv;
#pragma unroll
    for (int off = 32; off; off >>= 1) ssq += __shfl_down(ssq, off, 64);
    __shared__ float red2[2];
    __shared__ float xn[HD];
    if ((d & 63) == 0) red2[d >> 6] = ssq;
    __syncthreads();
    const float rs = rsqrtf((red2[0] + red2[1]) * (1.f / HD) + EPSF);
    const float nv = vv * rs * w[d];
    xn[d] = nv;
    __syncthreads();
    const float p = (float)pos[s];
    const int i = d & 63;
    const float inv_freq = expf(-0.14391156698f * (float)i);
    const float ang = p * inv_freq;
    float sn, cs;
    sincosf(ang, &sn, &cs);
    const float rot = (d < 64) ? -xn[d + 64] : xn[d - 64];
    xr[d] = nv * cs + rot * sn;
}

// ---------------- flash-style causal GQA attention, no spills ----------------
// LDS: Qt (32KB) + K^T (32KB). V read straight from L2 in PV.
__global__ __launch_bounds__(256) void attn3_kernel(
    const float* __restrict__ Q, const float* __restrict__ K,
    const float* __restrict__ V, float* __restrict__ O)
{
    __shared__ float Qt[128 * 64];
    __shared__ float KT[128 * 64];

    const int h = blockIdx.y;
    const int bx = blockIdx.x;
    const int qt_idx = (bx & 1) ? (31 - (bx >> 1)) : (bx >> 1);
    const int q0 = qt_idx * 64;
    const int kvh = h >> 1;
    const int tid = threadIdx.x;
    const int tr = tid >> 4, tc = tid & 15;
    const int lane = tid & 63;
    const int gbase = lane & 48;
    const int nt = (q0 >> 6) + 1;
    const float scale = 0.08838834764831845f;

    {
        const int qr = tid & 63;
        const int dbase = (tid >> 6) * 4;
        const float* qp = Q + (size_t)(q0 + qr) * (NHQ * HD) + h * HD;
#pragma unroll
        for (int it = 0; it < 8; ++it) {
            const int d0 = dbase + it * 16;
            float4 qv = *reinterpret_cast<const float4*>(qp + d0);
            Qt[(d0 + 0) * 64 + qr] = qv.x * scale;
            Qt[(d0 + 1) * 64 + qr] = qv.y * scale;
            Qt[(d0 + 2) * 64 + qr] = qv.z * scale;
            Qt[(d0 + 3) * 64 + qr] = qv.w * scale;
        }
    }

    const int kj = tid & 63;
    const int kd = (tid >> 6) * 4;
    const float* kbp = K + (size_t)kvh * HD + kd;
    float4 kreg[8];
#pragma unroll
    for (int it = 0; it < 8; ++it)
        kreg[it] = *reinterpret_cast<const float4*>(kbp + (size_t)kj * (NKV * HD) + it * 16);

    float sc[4][4], p[4][4];
    float4 oA[4], oB[4];
    float mrow[4], lrow[4];
#pragma unroll
    for (int i = 0; i < 4; ++i) {
        oA[i] = make_float4(0.f, 0.f, 0.f, 0.f);
        oB[i] = make_float4(0.f, 0.f, 0.f, 0.f);
        mrow[i] = -INFINITY; lrow[i] = 0.f;
    }

    for (int t = 0; t < nt; ++t) {
        const int j0 = t * 64;
        __syncthreads();                 // prev scores done reading KT
#pragma unroll
        for (int it = 0; it < 8; ++it) {
            const int d0 = kd + it * 16;
            KT[(d0 + 0) * 64 + kj] = kreg[it].x;
            KT[(d0 + 1) * 64 + kj] = kreg[it].y;
            KT[(d0 + 2) * 64 + kj] = kreg[it].z;
            KT[(d0 + 3) * 64 + kj] = kreg[it].w;
        }
        __syncthreads();
        if (t + 1 < nt) {                // prefetch next K tile under compute
#pragma unroll
            for (int it = 0; it < 8; ++it)
                kreg[it] = *reinterpret_cast<const float4*>(
                    kbp + (size_t)((t + 1) * 64 + kj) * (NKV * HD) + it * 16);
        }

        // scores
#pragma unroll
        for (int i = 0; i < 4; ++i)
#pragma unroll
            for (int c = 0; c < 4; ++c) sc[i][c] = 0.f;
#pragma unroll 4
        for (int kk = 0; kk < 128; ++kk) {
            float4 qv = *reinterpret_cast<const float4*>(&Qt[kk * 64 + tr * 4]);
            float4 kv = *reinterpret_cast<const float4*>(&KT[kk * 64 + tc * 4]);
            float qa[4] = {qv.x, qv.y, qv.z, qv.w};
            float ka[4] = {kv.x, kv.y, kv.z, kv.w};
#pragma unroll
            for (int i = 0; i < 4; ++i)
#pragma unroll
                for (int c = 0; c < 4; ++c)
                    sc[i][c] += qa[i] * ka[c];
        }

        if (j0 == q0) {
#pragma unroll
            for (int i = 0; i < 4; ++i) {
                const int r = tr * 4 + i;
#pragma unroll
                for (int c = 0; c < 4; ++c)
                    if (tc * 4 + c > r) sc[i][c] = -INFINITY;
            }
        }

#pragma unroll
        for (int i = 0; i < 4; ++i) {
            float rm = fmaxf(fmaxf(sc[i][0], sc[i][1]), fmaxf(sc[i][2], sc[i][3]));
            rm = fmaxf(rm, __shfl_xor(rm, 1, 64));
            rm = fmaxf(rm, __shfl_xor(rm, 2, 64));
            rm = fmaxf(rm, __shfl_xor(rm, 4, 64));
            rm = fmaxf(rm, __shfl_xor(rm, 8, 64));
            const float mnew = fmaxf(mrow[i], rm);
            const float fac = expf(mrow[i] - mnew);
            mrow[i] = mnew;
            float rsum = 0.f;
#pragma unroll
            for (int c = 0; c < 4; ++c) {
                const float e = expf(sc[i][c] - mnew);
                p[i][c] = e; rsum += e;
            }
            rsum += __shfl_xor(rsum, 1, 64);
            rsum += __shfl_xor(rsum, 2, 64);
            rsum += __shfl_xor(rsum, 4, 64);
            rsum += __shfl_xor(rsum, 8, 64);
            lrow[i] = lrow[i] * fac + rsum;
            oA[i].x *= fac; oA[i].y *= fac; oA[i].z *= fac; oA[i].w *= fac;
            oB[i].x *= fac; oB[i].y *= fac; oB[i].z *= fac; oB[i].w *= fac;
        }

        // PV: V rows straight from global (L2-resident), P broadcast via shfl
        const float* vb = V + (size_t)j0 * (NKV * HD) + kvh * HD + tc * 8;
#pragma unroll
        for (int j4 = 0; j4 < 16; ++j4) {
            float pb[4][4];
#pragma unroll
            for (int i = 0; i < 4; ++i)
#pragma unroll
                for (int c = 0; c < 4; ++c)
                    pb[i][c] = __shfl(p[i][c], gbase + j4, 64);
#pragma unroll
            for (int c = 0; c < 4; ++c) {
                const int j = j4 * 4 + c;
                const float* vr = vb + (size_t)j * (NKV * HD);
                float4 v0 = *reinterpret_cast<const float4*>(vr);
                float4 v1 = *reinterpret_cast<const float4*>(vr + 4);
#pragma unroll
                for (int i = 0; i < 4; ++i) {
                    oA[i].x += pb[i][c] * v0.x; oA[i].y += pb[i][c] * v0.y;
                    oA[i].z += pb[i][c] * v0.z; oA[i].w += pb[i][c] * v0.w;
                    oB[i].x += pb[i][c] * v1.x; oB[i].y += pb[i][c] * v1.y;
                    oB[i].z += pb[i][c] * v1.z; oB[i].w += pb[i][c] * v1.w;
                }
            }
        }
    }

#pragma unroll
    for (int i = 0; i < 4; ++i) {
        const float inv = 1.f / lrow[i];
        float4 a = oA[i], b = oB[i];
        a.x *= inv; a.y *= inv; a.z *= inv; a.w *= inv;
        b.x *= inv; b.y *= inv; b.z *= inv; b.w *= inv;
        const size_t off = (size_t)(q0 + tr * 4 + i) * (NHQ * HD) + h * HD + tc * 8;
        *reinterpret_cast<float4*>(O + off) = a;
        *reinterpret_cast<float4*>(O + off + 4) = b;
    }
}

extern "C" void kernel_launch(void* const* d_in, const int* in_sizes, int n_in,
                              void* d_out, int out_size, void* d_ws, size_t ws_size,
                              hipStream_t stream)
{
    const float* x     = (const float*)d_in[0];
    const int*   pos   = (const int*)d_in[1];
    const float* w_in  = (const float*)d_in[2];
    const float* wq    = (const float*)d_in[3];
    const float* wk    = (const float*)d_in[4];
    const float* wv    = (const float*)d_in[5];
    const float* qnw   = (const float*)d_in[6];
    const float* knw   = (const float*)d_in[7];
    const float* wo    = (const float*)d_in[8];
    const float* wpost = (const float*)d_in[9];
    const float* wgate = (const float*)d_in[10];
    const float* wup   = (const float*)d_in[11];
    const float* wdown = (const float*)d_in[12];
    float* out = (float*)d_out;

    float* ws   = (float*)d_ws;
    float* h    = ws;                             // SEQ*HSZ fp32 (norm out, later attn out)
    float* q    = h + (size_t)SEQ * HSZ;          // SEQ*NHQ*HD fp32 (later h2 planes)
    float* k    = q + (size_t)SEQ * NHQ * HD;
    float* v    = k + (size_t)SEQ * NKV * HD;
    float* gate = v + (size_t)SEQ * NKV * HD;     // SEQ*IMS fp32
    unsigned short* gah = (unsigned short*)(gate + (size_t)SEQ * IMS);  // SEQ*IMS bf16
    unsigned short* gal = gah + (size_t)SEQ * IMS;
    unsigned short* wbh = gal + (size_t)SEQ * IMS;                      // HSZ*IMS bf16 (reused 3x)
    unsigned short* wbl = wbh + (size_t)HSZ * IMS;
    unsigned short* h2h = (unsigned short*)q;                           // SEQ*HSZ bf16 (aliases q)
    unsigned short* h2l = h2h + (size_t)SEQ * HSZ;

    // --- attention sub-block (fp32 path) ---
    rmsnorm_kernel<<<SEQ, 256, 0, stream>>>(x, w_in, h, HSZ);
    sgemm128<<<dim3((NHQ * HD) / 128, SEQ / 128), 256, 0, stream>>>(h, wq, nullptr, q, SEQ, NHQ * HD, HSZ);
    sgemm128<<<dim3((NKV * HD) / 128, SEQ / 128), 256, 0, stream>>>(h, wk, nullptr, k, SEQ, NKV * HD, HSZ);
    sgemm128<<<dim3((NKV * HD) / 128, SEQ / 128), 256, 0, stream>>>(h, wv, nullptr, v, SEQ, NKV * HD, HSZ);
    qknorm_rope_kernel<<<SEQ * NHQ, 128, 0, stream>>>(q, qnw, pos, NHQ);
    qknorm_rope_kernel<<<SEQ * NKV, 128, 0, stream>>>(k, knw, pos, NKV);
    attn3_kernel<<<dim3(SEQ / 64, NHQ), 256, 0, stream>>>(q, k, v, h);
    sgemm128<<<dim3(HSZ / 128, SEQ / 128), 256, 0, stream>>>(h, wo, x, out, SEQ, HSZ, NHQ * HD);

    // --- MLP sub-block (bf16x3 MFMA path) ---
    rmsnorm_planes_kernel<<<SEQ, 256, 0, stream>>>(out, wpost, h2h, h2l, HSZ, SEQ);
    wconv_kernel<<<(HSZ / 8) * IMS / 256, 256, 0, stream>>>(wgate, wbh, wbl, HSZ, IMS);
    mgemm3<0><<<dim3(IMS / 128, SEQ / 128), 256, 0, stream>>>(
        h2h, h2l, wbh, wbl, nullptr, gate, nullptr, nullptr, SEQ, IMS, HSZ);
    wconv_kernel<<<(HSZ / 8) * IMS / 256, 256, 0, stream>>>(wup, wbh, wbl, HSZ, IMS);
    mgemm3<1><<<dim3(IMS / 128, SEQ / 128), 256, 0, stream>>>(
        h2h, h2l, wbh, wbl, gate, nullptr, gah, gal, SEQ, IMS, HSZ);
    wconv_kernel<<<(IMS / 8) * HSZ / 256, 256, 0, stream>>>(wdown, wbh, wbl, IMS, HSZ);
    mgemm3<0><<<dim3(HSZ / 128, SEQ / 128), 256, 0, stream>>>(
        gah, gal, wbh, wbl, out, out, nullptr, nullptr, SEQ, HSZ, IMS);
}

// Round 6
// 2664.985 us; speedup vs baseline: 1.7217x; 1.2180x over previous
//
#include <hip/hip_runtime.h>
#include <math.h>

#define SEQ   2048
#define HSZ   2048
#define NHQ   16
#define NKV   8
#define HD    128
#define IMS   6144
#define EPSF  1e-6f

typedef float f32x4 __attribute__((ext_vector_type(4)));
typedef short s16x8 __attribute__((ext_vector_type(8)));

__device__ __forceinline__ unsigned short f2bf(float f) {
    unsigned int u = __float_as_uint(f);
    unsigned int r = (u + 0x7FFFu + ((u >> 16) & 1u)) >> 16;   // RNE
    return (unsigned short)r;
}
__device__ __forceinline__ float bf2f(unsigned short h) {
    return __uint_as_float(((unsigned int)h) << 16);
}

// ---------------- row-wise RMSNorm -> fp32 ----------------
__global__ __launch_bounds__(256) void rmsnorm_kernel(
    const float* __restrict__ x, const float* __restrict__ w,
    float* __restrict__ out, int ncols)
{
    const int row = blockIdx.x;
    const float* xr = x + (size_t)row * ncols;
    float* orow = out + (size_t)row * ncols;
    float ssq = 0.f;
    for (int c = threadIdx.x * 4; c < ncols; c += 256 * 4) {
        float4 v = *reinterpret_cast<const float4*>(xr + c);
        ssq += v.x*v.x + v.y*v.y + v.z*v.z + v.w*v.w;
    }
#pragma unroll
    for (int off = 32; off; off >>= 1) ssq += __shfl_down(ssq, off, 64);
    __shared__ float red[4];
    __shared__ float rs_s;
    if ((threadIdx.x & 63) == 0) red[threadIdx.x >> 6] = ssq;
    __syncthreads();
    if (threadIdx.x == 0) {
        float t = red[0] + red[1] + red[2] + red[3];
        rs_s = rsqrtf(t / (float)ncols + EPSF);
    }
    __syncthreads();
    const float rs = rs_s;
    for (int c = threadIdx.x * 4; c < ncols; c += 256 * 4) {
        float4 v = *reinterpret_cast<const float4*>(xr + c);
        float4 g = *reinterpret_cast<const float4*>(w + c);
        float4 o;
        o.x = v.x * rs * g.x; o.y = v.y * rs * g.y;
        o.z = v.z * rs * g.z; o.w = v.w * rs * g.w;
        *reinterpret_cast<float4*>(orow + c) = o;
    }
}

// ------- RMSNorm -> bf16 hi/lo planes in A-role k-blocked layout -------
__global__ __launch_bounds__(256) void rmsnorm_planes_kernel(
    const float* __restrict__ x, const float* __restrict__ w,
    unsigned short* __restrict__ Ph, unsigned short* __restrict__ Pl,
    int ncols, int M)
{
    const int row = blockIdx.x;
    const float* xr = x + (size_t)row * ncols;
    const int c0 = threadIdx.x * 8;
    float4 v0 = *reinterpret_cast<const float4*>(xr + c0);
    float4 v1 = *reinterpret_cast<const float4*>(xr + c0 + 4);
    float ssq = v0.x*v0.x + v0.y*v0.y + v0.z*v0.z + v0.w*v0.w
              + v1.x*v1.x + v1.y*v1.y + v1.z*v1.z + v1.w*v1.w;
#pragma unroll
    for (int off = 32; off; off >>= 1) ssq += __shfl_down(ssq, off, 64);
    __shared__ float red[4];
    __shared__ float rs_s;
    if ((threadIdx.x & 63) == 0) red[threadIdx.x >> 6] = ssq;
    __syncthreads();
    if (threadIdx.x == 0)
        rs_s = rsqrtf((red[0] + red[1] + red[2] + red[3]) / (float)ncols + EPSF);
    __syncthreads();
    const float rs = rs_s;
    float vals[8] = {v0.x, v0.y, v0.z, v0.w, v1.x, v1.y, v1.z, v1.w};
    unsigned short hh[8], ll[8];
#pragma unroll
    for (int i = 0; i < 8; ++i) {
        float f = vals[i] * rs * w[c0 + i];
        hh[i] = f2bf(f);
        ll[i] = f2bf(f - bf2f(hh[i]));
    }
    const size_t boff = ((size_t)threadIdx.x * M + row) * 8;
    uint4 ph, pl;
    ph.x = hh[0] | (hh[1] << 16); ph.y = hh[2] | (hh[3] << 16);
    ph.z = hh[4] | (hh[5] << 16); ph.w = hh[6] | (hh[7] << 16);
    pl.x = ll[0] | (ll[1] << 16); pl.y = ll[2] | (ll[3] << 16);
    pl.z = ll[4] | (ll[5] << 16); pl.w = ll[6] | (ll[7] << 16);
    *reinterpret_cast<uint4*>(Ph + boff) = ph;
    *reinterpret_cast<uint4*>(Pl + boff) = pl;
}

// ------- weight fp32 [K][N] -> bf16 hi/lo planes, B-role k-blocked -------
__global__ __launch_bounds__(256) void wconv_kernel(
    const float* __restrict__ W, unsigned short* __restrict__ Ph,
    unsigned short* __restrict__ Pl, int Kd, int Nd)
{
    const int idx = blockIdx.x * 256 + threadIdx.x;
    const int total = (Kd >> 3) * Nd;
    if (idx >= total) return;
    const int kb = idx / Nd;
    const int n  = idx - kb * Nd;
    unsigned short hh[8], ll[8];
#pragma unroll
    for (int i = 0; i < 8; ++i) {
        float f = W[(size_t)(kb * 8 + i) * Nd + n];
        hh[i] = f2bf(f);
        ll[i] = f2bf(f - bf2f(hh[i]));
    }
    uint4 ph, pl;
    ph.x = hh[0] | (hh[1] << 16); ph.y = hh[2] | (hh[3] << 16);
    ph.z = hh[4] | (hh[5] << 16); ph.w = hh[6] | (hh[7] << 16);
    pl.x = ll[0] | (ll[1] << 16); pl.y = ll[2] | (ll[3] << 16);
    pl.z = ll[4] | (ll[5] << 16); pl.w = ll[6] | (ll[7] << 16);
    *reinterpret_cast<uint4*>(Ph + (size_t)idx * 8) = ph;
    *reinterpret_cast<uint4*>(Pl + (size_t)idx * 8) = pl;
}

// ---------------- SGEMM (fp32, qkv projections) ----------------
__global__ __launch_bounds__(256) void sgemm128(
    const float* __restrict__ A, const float* __restrict__ B,
    const float* __restrict__ R, float* __restrict__ C,
    int M, int N, int K)
{
    __shared__ float As[16][128];
    __shared__ float Bs[16][128];
    const int tid = threadIdx.x;
    const int tx = tid & 15;
    const int ty = tid >> 4;
    const int bm = blockIdx.y, bn = blockIdx.x;
    const int arow = tid >> 2;
    const int acol = (tid & 3) << 2;
    const int brow = tid >> 5;
    const int bcol = (tid & 31) << 2;
    const float* Ap = A + (size_t)(bm * 128 + arow) * K + acol;
    const float* Bp = B + (size_t)brow * N + bn * 128 + bcol;
    float acc[8][8] = {};

    float4 a0 = *reinterpret_cast<const float4*>(Ap);
    float4 a1 = *reinterpret_cast<const float4*>(Ap + (size_t)64 * K);
    float4 b0 = *reinterpret_cast<const float4*>(Bp);
    float4 b1 = *reinterpret_cast<const float4*>(Bp + (size_t)8 * N);

    for (int k0 = 0;;) {
        __syncthreads();
        As[acol + 0][arow] = a0.x; As[acol + 1][arow] = a0.y;
        As[acol + 2][arow] = a0.z; As[acol + 3][arow] = a0.w;
        As[acol + 0][arow + 64] = a1.x; As[acol + 1][arow + 64] = a1.y;
        As[acol + 2][arow + 64] = a1.z; As[acol + 3][arow + 64] = a1.w;
        *reinterpret_cast<float4*>(&Bs[brow][bcol]) = b0;
        *reinterpret_cast<float4*>(&Bs[brow + 8][bcol]) = b1;
        __syncthreads();
        const int kn = k0 + 16;
        float4 na0, na1, nb0, nb1;
        if (kn < K) {
            na0 = *reinterpret_cast<const float4*>(Ap + kn);
            na1 = *reinterpret_cast<const float4*>(Ap + (size_t)64 * K + kn);
            nb0 = *reinterpret_cast<const float4*>(Bp + (size_t)kn * N);
            nb1 = *reinterpret_cast<const float4*>(Bp + (size_t)(kn + 8) * N);
        }
#pragma unroll
        for (int kk = 0; kk < 16; ++kk) {
            float4 av0 = *reinterpret_cast<const float4*>(&As[kk][ty * 8]);
            float4 av1 = *reinterpret_cast<const float4*>(&As[kk][ty * 8 + 4]);
            float4 bv0 = *reinterpret_cast<const float4*>(&Bs[kk][tx * 8]);
            float4 bv1 = *reinterpret_cast<const float4*>(&Bs[kk][tx * 8 + 4]);
            float a[8] = {av0.x, av0.y, av0.z, av0.w, av1.x, av1.y, av1.z, av1.w};
            float b[8] = {bv0.x, bv0.y, bv0.z, bv0.w, bv1.x, bv1.y, bv1.z, bv1.w};
#pragma unroll
            for (int i = 0; i < 8; ++i)
#pragma unroll
                for (int j = 0; j < 8; ++j)
                    acc[i][j] += a[i] * b[j];
        }
        if (kn >= K) break;
        a0 = na0; a1 = na1; b0 = nb0; b1 = nb1;
        k0 = kn;
    }

    const int row0 = bm * 128 + ty * 8;
    const int col0 = bn * 128 + tx * 8;
#pragma unroll
    for (int i = 0; i < 8; ++i) {
        size_t off = (size_t)(row0 + i) * N + col0;
        float4 o0 = make_float4(acc[i][0], acc[i][1], acc[i][2], acc[i][3]);
        float4 o1 = make_float4(acc[i][4], acc[i][5], acc[i][6], acc[i][7]);
        if (R) {
            float4 r0 = *reinterpret_cast<const float4*>(R + off);
            float4 r1 = *reinterpret_cast<const float4*>(R + off + 4);
            o0.x += r0.x; o0.y += r0.y; o0.z += r0.z; o0.w += r0.w;
            o1.x += r1.x; o1.y += r1.y; o1.z += r1.z; o1.w += r1.w;
        }
        *reinterpret_cast<float4*>(C + off) = o0;
        *reinterpret_cast<float4*>(C + off + 4) = o1;
    }
}

// -------- MFMA bf16x3 GEMM: C = (Ah+Al)@(Bh+Bl), fp32 accumulate --------
template<int EPI>
__global__ __launch_bounds__(256) void mgemm3(
    const unsigned short* __restrict__ Ah, const unsigned short* __restrict__ Al,
    const unsigned short* __restrict__ Bh, const unsigned short* __restrict__ Bl,
    const float* __restrict__ X, float* __restrict__ C,
    unsigned short* __restrict__ Oh, unsigned short* __restrict__ Ol,
    int M, int N, int K)
{
    __shared__ uint4 Sl[4][512];

    const int tid  = threadIdx.x;
    const int lane = tid & 63;
    const int wid  = tid >> 6;
    const int wm   = wid >> 1, wn = wid & 1;
    const int bm = blockIdx.y, bn = blockIdx.x;

    const uint4* gplane;
    {
        const unsigned short* p = (wid == 0) ? Ah : (wid == 1) ? Al : (wid == 2) ? Bh : Bl;
        gplane = reinterpret_cast<const uint4*>(p);
    }
    const int pdim  = (wid < 2) ? M : N;
    const int pbase = (wid < 2) ? bm * 128 : bn * 128;

    f32x4 acc[4][4];
#pragma unroll
    for (int i = 0; i < 4; ++i)
#pragma unroll
        for (int j = 0; j < 4; ++j)
            acc[i][j] = (f32x4){0.f, 0.f, 0.f, 0.f};

    const int steps = K >> 5;
    uint4 rg[8];
#pragma unroll
    for (int i = 0; i < 8; ++i) {
        const int kb = i >> 1, idx = (i & 1) * 64 + lane;
        rg[i] = gplane[(size_t)kb * pdim + pbase + idx];
    }

    for (int s = 0; s < steps; ++s) {
        __syncthreads();
#pragma unroll
        for (int i = 0; i < 8; ++i) {
            const int kb = i >> 1, idx = (i & 1) * 64 + lane;
            Sl[wid][kb * 128 + idx] = rg[i];
        }
        __syncthreads();
        if (s + 1 < steps) {
            const size_t kb0 = (size_t)(s + 1) * 4;
#pragma unroll
            for (int i = 0; i < 8; ++i) {
                const int kb = i >> 1, idx = (i & 1) * 64 + lane;
                rg[i] = gplane[(kb0 + kb) * pdim + pbase + idx];
            }
        }
        const int kq = (lane >> 4) * 128 + (lane & 15);
        s16x8 bh[4], bl[4];
#pragma unroll
        for (int nf = 0; nf < 4; ++nf) {
            bh[nf] = *reinterpret_cast<const s16x8*>(&Sl[2][kq + wn * 64 + nf * 16]);
            bl[nf] = *reinterpret_cast<const s16x8*>(&Sl[3][kq + wn * 64 + nf * 16]);
        }
#pragma unroll
        for (int mf = 0; mf < 4; ++mf) {
            s16x8 ah = *reinterpret_cast<const s16x8*>(&Sl[0][kq + wm * 64 + mf * 16]);
            s16x8 al = *reinterpret_cast<const s16x8*>(&Sl[1][kq + wm * 64 + mf * 16]);
#pragma unroll
            for (int nf = 0; nf < 4; ++nf) {
                acc[mf][nf] = __builtin_amdgcn_mfma_f32_16x16x32_bf16(ah, bh[nf], acc[mf][nf], 0, 0, 0);
                acc[mf][nf] = __builtin_amdgcn_mfma_f32_16x16x32_bf16(al, bh[nf], acc[mf][nf], 0, 0, 0);
                acc[mf][nf] = __builtin_amdgcn_mfma_f32_16x16x32_bf16(ah, bl[nf], acc[mf][nf], 0, 0, 0);
            }
        }
    }

    const int lrow = (lane >> 4) * 4;
    const int lcol = lane & 15;
#pragma unroll
    for (int mf = 0; mf < 4; ++mf) {
#pragma unroll
        for (int nf = 0; nf < 4; ++nf) {
            const int col = bn * 128 + wn * 64 + nf * 16 + lcol;
            const int row0 = bm * 128 + wm * 64 + mf * 16 + lrow;
#pragma unroll
            for (int r = 0; r < 4; ++r) {
                const int row = row0 + r;
                float val = acc[mf][nf][r];
                if (EPI == 0) {
                    if (X) val += X[(size_t)row * N + col];
                    C[(size_t)row * N + col] = val;
                } else {
                    const float g = X[(size_t)row * N + col];
                    const float sg = g / (1.f + expf(-g));
                    const float v = sg * val;
                    const unsigned short h = f2bf(v);
                    const unsigned short l = f2bf(v - bf2f(h));
                    const size_t po = ((size_t)(col >> 3) * M + row) * 8 + (col & 7);
                    Oh[po] = h;
                    Ol[po] = l;
                }
            }
        }
    }
}

// ------- per-head RMSNorm + RoPE -> bf16 plane(s), k-blocked per head -------
// plane element (seq s, dim d) of head hh at [((hh*16 + (d>>3))*2048 + s)*8 + (d&7)]
__global__ __launch_bounds__(128) void qknorm_rope2_kernel(
    const float* __restrict__ x, const float* __restrict__ w,
    const int* __restrict__ pos, unsigned short* __restrict__ Ph,
    unsigned short* __restrict__ Pl, int nheads, float scale)
{
    const int blk = blockIdx.x;
    const int s = blk / nheads, hh = blk - s * nheads;
    const float* xr = x + ((size_t)s * nheads + hh) * HD;
    const int d = threadIdx.x;
    float vv = xr[d];
    float ssq = vv * vv;
#pragma unroll
    for (int off = 32; off; off >>= 1) ssq += __shfl_down(ssq, off, 64);
    __shared__ float red2[2];
    __shared__ float xn[HD];
    if ((d & 63) == 0) red2[d >> 6] = ssq;
    __syncthreads();
    const float rs = rsqrtf((red2[0] + red2[1]) * (1.f / HD) + EPSF);
    const float nv = vv * rs * w[d];
    xn[d] = nv;
    __syncthreads();
    const float p = (float)pos[s];
    const int i = d & 63;
    const float inv_freq = expf(-0.14391156698f * (float)i);
    const float ang = p * inv_freq;
    float sn, cs;
    sincosf(ang, &sn, &cs);
    const float rot = (d < 64) ? -xn[d + 64] : xn[d - 64];
    const float val = (nv * cs + rot * sn) * scale;
    const unsigned short hi = f2bf(val);
    const size_t idx = ((size_t)(hh * 16 + (d >> 3)) * 2048 + s) * 8 + (d & 7);
    Ph[idx] = hi;
    if (Pl) Pl[idx] = f2bf(val - bf2f(hi));
}

// ------- V fp32 [s][kvh][d] -> bf16 plane key-blocked: [kvh][((k>>3)*128+d)*8+(k&7)] -------
__global__ __launch_bounds__(256) void vconv_kernel(
    const float* __restrict__ v, unsigned short* __restrict__ Vp)
{
    const int kvh = blockIdx.y;
    const int k0 = blockIdx.x * 64;
    const int d = threadIdx.x & 127;
    const int half = threadIdx.x >> 7;
    uint4* Vp4 = reinterpret_cast<uint4*>(Vp) + (size_t)kvh * 256 * 128;
#pragma unroll
    for (int kb = half * 4; kb < half * 4 + 4; ++kb) {
        unsigned short t8[8];
#pragma unroll
        for (int j = 0; j < 8; ++j)
            t8[j] = f2bf(v[(size_t)(k0 + kb * 8 + j) * (NKV * HD) + kvh * HD + d]);
        uint4 u;
        u.x = (unsigned)t8[0] | ((unsigned)t8[1] << 16);
        u.y = (unsigned)t8[2] | ((unsigned)t8[3] << 16);
        u.z = (unsigned)t8[4] | ((unsigned)t8[5] << 16);
        u.w = (unsigned)t8[6] | ((unsigned)t8[7] << 16);
        Vp4[(size_t)((k0 >> 3) + kb) * 128 + d] = u;
    }
}

// ---------------- MFMA flash attention ----------------
// block = 128 queries x 1 head (4 waves x 32 queries), 64-key tiles.
// Q: dual-plane bf16 in regs (pre-scaled). K/V/P single-plane bf16.
// Output written as hi/lo A-planes for the wo GEMM.
__global__ __launch_bounds__(256) void attn4_kernel(
    const unsigned short* __restrict__ Qh, const unsigned short* __restrict__ Ql,
    const unsigned short* __restrict__ Kh, const unsigned short* __restrict__ Vh,
    unsigned short* __restrict__ Oh, unsigned short* __restrict__ Ol)
{
    __shared__ uint4 sK[16 * 65];                       // [dblk][key + pad]
    __shared__ uint4 sV[8 * 129];                       // [keyblk][d + pad]
    __shared__ __align__(16) unsigned short sP[4][32 * 72];  // per-wave P, padded rows

    const int h = blockIdx.y;
    const int kvh = h >> 1;
    const int qb0 = blockIdx.x * 128;
    const int tid = threadIdx.x;
    const int lane = tid & 63;
    const int w = tid >> 6;
    const int g = lane >> 4;
    const int l15 = lane & 15;
    const int qw0 = qb0 + w * 32;

    const uint4* Qh4 = reinterpret_cast<const uint4*>(Qh) + (size_t)h * 16 * 2048;
    const uint4* Ql4 = reinterpret_cast<const uint4*>(Ql) + (size_t)h * 16 * 2048;
    s16x8 qfh[2][4], qfl[2][4];
#pragma unroll
    for (int mf = 0; mf < 2; ++mf)
#pragma unroll
        for (int kb = 0; kb < 4; ++kb) {
            const int idx = (kb * 4 + g) * 2048 + qw0 + mf * 16 + l15;
            uint4 a = Qh4[idx], b = Ql4[idx];
            qfh[mf][kb] = *reinterpret_cast<s16x8*>(&a);
            qfl[mf][kb] = *reinterpret_cast<s16x8*>(&b);
        }

    f32x4 o[2][8];
    float m[2][4], lsum[2][4];
#pragma unroll
    for (int mf = 0; mf < 2; ++mf) {
#pragma unroll
        for (int f = 0; f < 8; ++f) o[mf][f] = (f32x4){0.f, 0.f, 0.f, 0.f};
#pragma unroll
        for (int r = 0; r < 4; ++r) { m[mf][r] = -INFINITY; lsum[mf][r] = 0.f; }
    }

    const uint4* Kg0 = reinterpret_cast<const uint4*>(Kh) + (size_t)kvh * 16 * 2048;
    const uint4* Vg0 = reinterpret_cast<const uint4*>(Vh) + (size_t)kvh * 256 * 128;

    const int nt = qb0 / 64 + 2;
    for (int t = 0; t < nt; ++t) {
        const int j0 = t * 64;
        __syncthreads();
        {
            const int dblk = tid >> 4, kk = tid & 15;
            const uint4* Kg = Kg0 + j0;
#pragma unroll
            for (int s = 0; s < 4; ++s)
                sK[dblk * 65 + kk + s * 16] = Kg[(size_t)dblk * 2048 + kk + s * 16];
            const int kl = tid >> 5, dd = tid & 31;
            const uint4* Vg = Vg0 + (size_t)(j0 >> 3) * 128;
#pragma unroll
            for (int s = 0; s < 4; ++s)
                sV[kl * 129 + dd + s * 32] = Vg[(size_t)kl * 128 + dd + s * 32];
        }
        __syncthreads();
        if (j0 > qw0 + 31) continue;      // fully masked for this wave

        // ---- QK^T ----
        f32x4 sc[2][4];
#pragma unroll
        for (int mf = 0; mf < 2; ++mf)
#pragma unroll
            for (int fc = 0; fc < 4; ++fc) sc[mf][fc] = (f32x4){0.f, 0.f, 0.f, 0.f};
#pragma unroll
        for (int kb = 0; kb < 4; ++kb)
#pragma unroll
            for (int fc = 0; fc < 4; ++fc) {
                uint4 kr = sK[(kb * 4 + g) * 65 + fc * 16 + l15];
                s16x8 kf = *reinterpret_cast<s16x8*>(&kr);
#pragma unroll
                for (int mf = 0; mf < 2; ++mf) {
                    sc[mf][fc] = __builtin_amdgcn_mfma_f32_16x16x32_bf16(qfh[mf][kb], kf, sc[mf][fc], 0, 0, 0);
                    sc[mf][fc] = __builtin_amdgcn_mfma_f32_16x16x32_bf16(qfl[mf][kb], kf, sc[mf][fc], 0, 0, 0);
                }
            }

        // ---- mask + online softmax ----
        const bool mk = (j0 + 63 > qw0);
#pragma unroll
        for (int mf = 0; mf < 2; ++mf)
#pragma unroll
            for (int r = 0; r < 4; ++r) {
                float sv0 = sc[mf][0][r], sv1 = sc[mf][1][r];
                float sv2 = sc[mf][2][r], sv3 = sc[mf][3][r];
                if (mk) {
                    const int q = qw0 + mf * 16 + g * 4 + r;
                    if (j0 +  0 + l15 > q) sv0 = -INFINITY;
                    if (j0 + 16 + l15 > q) sv1 = -INFINITY;
                    if (j0 + 32 + l15 > q) sv2 = -INFINITY;
                    if (j0 + 48 + l15 > q) sv3 = -INFINITY;
                }
                float rm = fmaxf(fmaxf(sv0, sv1), fmaxf(sv2, sv3));
                rm = fmaxf(rm, __shfl_xor(rm, 1, 64));
                rm = fmaxf(rm, __shfl_xor(rm, 2, 64));
                rm = fmaxf(rm, __shfl_xor(rm, 4, 64));
                rm = fmaxf(rm, __shfl_xor(rm, 8, 64));
                const float mn = fmaxf(m[mf][r], rm);
                const float fac = __expf(m[mf][r] - mn);
                m[mf][r] = mn;
                const float p0 = __expf(sv0 - mn), p1 = __expf(sv1 - mn);
                const float p2 = __expf(sv2 - mn), p3 = __expf(sv3 - mn);
                float rs = p0 + p1 + p2 + p3;
                rs += __shfl_xor(rs, 1, 64);
                rs += __shfl_xor(rs, 2, 64);
                rs += __shfl_xor(rs, 4, 64);
                rs += __shfl_xor(rs, 8, 64);
                lsum[mf][r] = lsum[mf][r] * fac + rs;
#pragma unroll
                for (int f = 0; f < 8; ++f) o[mf][f][r] *= fac;
                unsigned short* pw = &sP[w][(mf * 16 + g * 4 + r) * 72];
                pw[ 0 + l15] = f2bf(p0);
                pw[16 + l15] = f2bf(p1);
                pw[32 + l15] = f2bf(p2);
                pw[48 + l15] = f2bf(p3);
            }

        // ---- PV ----
#pragma unroll
        for (int ks = 0; ks < 2; ++ks) {
            s16x8 pa[2];
#pragma unroll
            for (int mf = 0; mf < 2; ++mf)
                pa[mf] = *reinterpret_cast<const s16x8*>(
                    &sP[w][(mf * 16 + l15) * 72 + ks * 32 + g * 8]);
#pragma unroll
            for (int f = 0; f < 8; ++f) {
                uint4 vr = sV[(ks * 4 + g) * 129 + f * 16 + l15];
                s16x8 vf = *reinterpret_cast<s16x8*>(&vr);
#pragma unroll
                for (int mf = 0; mf < 2; ++mf)
                    o[mf][f] = __builtin_amdgcn_mfma_f32_16x16x32_bf16(pa[mf], vf, o[mf][f], 0, 0, 0);
            }
        }
    }

    // ---- epilogue: normalize, emit hi/lo A-planes ----
#pragma unroll
    for (int mf = 0; mf < 2; ++mf) {
        float inv[4];
#pragma unroll
        for (int r = 0; r < 4; ++r) inv[r] = 1.f / lsum[mf][r];
#pragma unroll
        for (int f = 0; f < 8; ++f) {
            const int col = h * 128 + f * 16 + l15;
#pragma unroll
            for (int r = 0; r < 4; ++r) {
                const int row = qb0 + w * 32 + mf * 16 + g * 4 + r;
                const float val = o[mf][f][r] * inv[r];
                const size_t idx = ((size_t)(col >> 3) * 2048 + row) * 8 + (col & 7);
                const unsigned short hi = f2bf(val);
                Oh[idx] = hi;
                Ol[idx] = f2bf(val - bf2f(hi));
            }
        }
    }
}

extern "C" void kernel_launch(void* const* d_in, const int* in_sizes, int n_in,
                              void* d_out, int out_size, void* d_ws, size_t ws_size,
                              hipStream_t stream)
{
    const float* x     = (const float*)d_in[0];
    const int*   pos   = (const int*)d_in[1];
    const float* w_in  = (const float*)d_in[2];
    const float* wq    = (const float*)d_in[3];
    const float* wk    = (const float*)d_in[4];
    const float* wv    = (const float*)d_in[5];
    const float* qnw   = (const float*)d_in[6];
    const float* knw   = (const float*)d_in[7];
    const float* wo    = (const float*)d_in[8];
    const float* wpost = (const float*)d_in[9];
    const float* wgate = (const float*)d_in[10];
    const float* wup   = (const float*)d_in[11];
    const float* wdown = (const float*)d_in[12];
    float* out = (float*)d_out;

    const size_t M1 = 1024 * 1024;
    float* ws = (float*)d_ws;
    float* h    = ws;                    // 4M fl
    float* qf   = ws + 4 * M1;           // 4M fl (later h2 planes)
    float* kf   = ws + 8 * M1;           // 2M fl
    float* vf   = ws + 10 * M1;          // 2M fl
    // region E @12M fl (48MB): gate fp32  UNION  attn input planes
    float* gate = ws + 12 * M1;
    unsigned short* QhP = (unsigned short*)(ws + 12 * M1);   // 4M sh
    unsigned short* QlP = QhP + 4 * M1;                      // 4M sh
    unsigned short* KhP = QlP + 4 * M1;                      // 2M sh
    unsigned short* VhP = KhP + 2 * M1;                      // 2M sh
    // region F @24M fl (48MB): gah/gal  UNION  attn output planes
    unsigned short* gah = (unsigned short*)(ws + 24 * M1);   // 12M sh
    unsigned short* gal = gah + 12 * M1;                     // 12M sh
    unsigned short* OhP = (unsigned short*)(ws + 24 * M1);   // 4M sh
    unsigned short* OlP = OhP + 4 * M1;                      // 4M sh
    // region G @36M fl (48MB): weight planes (reused per GEMM)
    unsigned short* wbh = (unsigned short*)(ws + 36 * M1);   // 12M sh
    unsigned short* wbl = wbh + 12 * M1;                     // 12M sh
    // h2 planes alias qf (q fp32 dead after qknorm_rope2)
    unsigned short* h2h = (unsigned short*)qf;               // 4M sh
    unsigned short* h2l = h2h + 4 * M1;                      // 4M sh

    // --- attention sub-block ---
    rmsnorm_kernel<<<SEQ, 256, 0, stream>>>(x, w_in, h, HSZ);
    sgemm128<<<dim3((NHQ * HD) / 128, SEQ / 128), 256, 0, stream>>>(h, wq, nullptr, qf, SEQ, NHQ * HD, HSZ);
    sgemm128<<<dim3((NKV * HD) / 128, SEQ / 128), 256, 0, stream>>>(h, wk, nullptr, kf, SEQ, NKV * HD, HSZ);
    sgemm128<<<dim3((NKV * HD) / 128, SEQ / 128), 256, 0, stream>>>(h, wv, nullptr, vf, SEQ, NKV * HD, HSZ);
    qknorm_rope2_kernel<<<SEQ * NHQ, 128, 0, stream>>>(qf, qnw, pos, QhP, QlP, NHQ, 0.08838834764831845f);
    qknorm_rope2_kernel<<<SEQ * NKV, 128, 0, stream>>>(kf, knw, pos, KhP, nullptr, NKV, 1.0f);
    vconv_kernel<<<dim3(32, NKV), 256, 0, stream>>>(vf, VhP);
    attn4_kernel<<<dim3(SEQ / 128, NHQ), 256, 0, stream>>>(QhP, QlP, KhP, VhP, OhP, OlP);
    wconv_kernel<<<(HSZ / 8) * HSZ / 256, 256, 0, stream>>>(wo, wbh, wbl, HSZ, HSZ);
    mgemm3<0><<<dim3(HSZ / 128, SEQ / 128), 256, 0, stream>>>(
        OhP, OlP, wbh, wbl, x, out, nullptr, nullptr, SEQ, HSZ, HSZ);

    // --- MLP sub-block ---
    rmsnorm_planes_kernel<<<SEQ, 256, 0, stream>>>(out, wpost, h2h, h2l, HSZ, SEQ);
    wconv_kernel<<<(HSZ / 8) * IMS / 256, 256, 0, stream>>>(wgate, wbh, wbl, HSZ, IMS);
    mgemm3<0><<<dim3(IMS / 128, SEQ / 128), 256, 0, stream>>>(
        h2h, h2l, wbh, wbl, nullptr, gate, nullptr, nullptr, SEQ, IMS, HSZ);
    wconv_kernel<<<(HSZ / 8) * IMS / 256, 256, 0, stream>>>(wup, wbh, wbl, HSZ, IMS);
    mgemm3<1><<<dim3(IMS / 128, SEQ / 128), 256, 0, stream>>>(
        h2h, h2l, wbh, wbl, gate, nullptr, gah, gal, SEQ, IMS, HSZ);
    wconv_kernel<<<(IMS / 8) * HSZ / 256, 256, 0, stream>>>(wdown, wbh, wbl, IMS, HSZ);
    mgemm3<0><<<dim3(HSZ / 128, SEQ / 128), 256, 0, stream>>>(
        gah, gal, wbh, wbl, out, out, nullptr, nullptr, SEQ, HSZ, IMS);
}